// Round 5
// baseline (180.159 us; speedup 1.0000x reference)
//
#include <hip/hip_runtime.h>
#include <math.h>

#define BB 32
#define CC 256
#define CQ 32      // C/8
#define NN 1024    // H*W

typedef short bf16x8 __attribute__((ext_vector_type(8)));
typedef float f32x4  __attribute__((ext_vector_type(4)));
typedef unsigned short u16;

// fp32 -> bf16 RNE
__device__ __forceinline__ u16 f2bf(float f) {
    unsigned u = __float_as_uint(f);
    u = (u + 0x7FFFu + ((u >> 16) & 1u)) >> 16;
    return (u16)u;
}

// pack two fp32 -> two bf16 in one u32 (single VALU op)
__device__ __forceinline__ unsigned cvt_pk_bf16(float lo, float hi) {
    unsigned r;
    asm("v_cvt_pk_bf16_f32 %0, %1, %2" : "=v"(r) : "v"(lo), "v"(hi));
    return r;
}

// ---------------------------------------------------------------------------
// Kernel 0: pack fused W = [Wq(32); Wk(32); Wv(256)] into MFMA A-frag order:
// wfrag[((rt*8 + kc)*64 + lane)*8 + j] = W[rt*16 + (lane&15)][kc*32 + (lane>>4)*8 + j]
// ---------------------------------------------------------------------------
__global__ void wpack_kernel(const float* __restrict__ Wq,
                             const float* __restrict__ Wk,
                             const float* __restrict__ Wv,
                             u16* __restrict__ wfrag)
{
    const int o = blockIdx.x * 256 + threadIdx.x;     // 0 .. 81919
    const int j    = o & 7;
    const int lane = (o >> 3) & 63;
    const int kc   = (o >> 9) & 7;
    const int rt   = o >> 12;                         // 0..19
    const int row  = rt * 16 + (lane & 15);
    const int col  = kc * 32 + (lane >> 4) * 8 + j;
    const float v = (row < 32) ? Wq[row * 256 + col]
                  : (row < 64) ? Wk[(row - 32) * 256 + col]
                               : Wv[(row - 64) * 256 + col];
    wfrag[o] = f2bf(v);
}

// ---------------------------------------------------------------------------
// Kernel 1: QKV projection. grid(32 n-tiles, 32 b), 256 thr, 4 blocks/CU.
// NEW this round: kt is written n-PERMUTED within each 32-row group
// (position q*4 + r + t*16 holds K row q*8 + t*4 + r) so that attn's
// swapped QK^T MFMA output lands directly in PV B-frag order (no LDS
// transpose needed in attn). qt/vv layouts unchanged.
// ---------------------------------------------------------------------------
struct QSmem {
    union {
        u16 xs[32][268];     // x^T tile [n][c] bf16, stride 268 (bank-spread)
        u16 osv[CC][40];     // v result [c][n]
    };
    u16 osqk[32][72];        // q|k result [n][d], d 0..31 = q, 32..63 = k
};

__global__ __launch_bounds__(256, 4) void qkv_kernel(
    const float* __restrict__ x, const u16* __restrict__ wfrag,
    const float* __restrict__ bq, const float* __restrict__ bk,
    const float* __restrict__ bv,
    u16* __restrict__ qt, u16* __restrict__ kt, u16* __restrict__ vv)
{
    __shared__ QSmem sm;
    const int b = blockIdx.y, n0 = blockIdx.x * 32;
    const int t = threadIdx.x;
    const int lane = t & 63, w = t >> 6;
    const int quad = lane >> 4, c16 = lane & 15;

    // ---- stage x^T bf16: 8 coalesced float4 loads, transpose-pack
    {
        const float* xb = x + (size_t)b * CC * NN + n0;
        const int n4 = (t & 7) * 4;       // n quad 0..28
        const int cr = t >> 3;            // 0..31: c within group of 32
        float4 f[8];
#pragma unroll
        for (int it = 0; it < 8; ++it)
            f[it] = *(const float4*)(xb + (size_t)(it * 32 + cr) * NN + n4);
#pragma unroll
        for (int it = 0; it < 8; ++it) {
            const int c = it * 32 + cr;
            sm.xs[n4 + 0][c] = f2bf(f[it].x);
            sm.xs[n4 + 1][c] = f2bf(f[it].y);
            sm.xs[n4 + 2][c] = f2bf(f[it].z);
            sm.xs[n4 + 3][c] = f2bf(f[it].w);
        }
    }
    __syncthreads();

    f32x4 acc[5][2];
#pragma unroll
    for (int i = 0; i < 5; ++i)
#pragma unroll
        for (int j = 0; j < 2; ++j) acc[i][j] = (f32x4){0.f, 0.f, 0.f, 0.f};

#pragma unroll 2
    for (int k = 0; k < 8; ++k) {
        const int c0 = k * 32;
        bf16x8 wa[5], xb[2];
#pragma unroll
        for (int rs = 0; rs < 5; ++rs)   // swizzled W: 16 B/lane contiguous
            wa[rs] = *(const bf16x8*)&wfrag[(size_t)(((w * 5 + rs) * 8 + k) * 64 + lane) * 8];
#pragma unroll
        for (int ns = 0; ns < 2; ++ns) { // B: n-col = lane&15, k=c=quad*8+j
            const short4 a = *(const short4*)&sm.xs[ns * 16 + c16][c0 + quad * 8];
            const short4 b2 = *(const short4*)&sm.xs[ns * 16 + c16][c0 + quad * 8 + 4];
            bf16x8 v;
            v[0] = a.x; v[1] = a.y; v[2] = a.z; v[3] = a.w;
            v[4] = b2.x; v[5] = b2.y; v[6] = b2.z; v[7] = b2.w;
            xb[ns] = v;
        }
#pragma unroll
        for (int rs = 0; rs < 5; ++rs)
#pragma unroll
            for (int ns = 0; ns < 2; ++ns)
                acc[rs][ns] = __builtin_amdgcn_mfma_f32_16x16x32_bf16(
                    wa[rs], xb[ns], acc[rs][ns], 0, 0, 0);
    }

    __syncthreads();   // xs dead; osv may alias it now

    // ---- scatter D + bias into LDS result tiles (bf16)
#pragma unroll
    for (int rs = 0; rs < 5; ++rs) {
#pragma unroll
        for (int r = 0; r < 4; ++r) {
            const int rg = w * 80 + rs * 16 + quad * 4 + r;
            const float bias = (rg < 32) ? bq[rg] : (rg < 64) ? bk[rg - 32] : bv[rg - 64];
#pragma unroll
            for (int ns = 0; ns < 2; ++ns) {
                const int n = ns * 16 + c16;
                const u16 h = f2bf(acc[rs][ns][r] + bias);
                if (rg < 64) sm.osqk[n][rg] = h;
                else         sm.osv[rg - 64][n] = h;
            }
        }
    }
    __syncthreads();

    // ---- coalesced global writes
    {
        // q|k: [32 n][32 d] each; threads 0..127 -> q, 128..255 -> k.
        // kt rows permuted within the 32-group: pos p holds n with
        // p = ((n&0x18)>>1) | ((n&4)<<2) | (n&3)  (q->bits3:2, t->bit4, r->1:0)
        const int o = (t & 127) * 8;                       // flat in [n][32]
        const int n = o >> 5, d = o & 31;
        if (t < 128) {
            const bf16x8 v = *(const bf16x8*)&sm.osqk[n][d];
            *(bf16x8*)&qt[((size_t)b * NN + n0) * CQ + n * 32 + d] = v;
        } else {
            const int p = ((n & 0x18) >> 1) | ((n & 4) << 2) | (n & 3);
            const bf16x8 v = *(const bf16x8*)&sm.osqk[n][d + 32];
            *(bf16x8*)&kt[((size_t)b * NN + n0) * CQ + p * 32 + d] = v;
        }
    }
#pragma unroll
    for (int it = 0; it < 4; ++it) {
        const int o = it * 2048 + t * 8;                   // flat in [256][32]
        const int c = o >> 5, n = o & 31;
        const bf16x8 v = *(const bf16x8*)&sm.osv[c][n];
        *(bf16x8*)&vv[((size_t)b * CC + c) * NN + n0 + n] = v;
    }
}

// ---------------------------------------------------------------------------
// Kernel 2: flash attention, ZERO LDS / ZERO barriers. r4 post-mortem: the
// P round-trip through LDS (12-cyc conflicted b128 reads, 2^21 conflict
// cycles, exact) + barrier rendezvous was the invariant binder across 4
// structural variants. Fix: swapped QK^T (mfma(K,Q) -> S^T in registers)
// with kt stored n-permuted so the S' output IS the PV B-frag (no
// cross-lane, no LDS). Wave owns m32 x c128; P never leaves registers;
// waves fully independent. lsum: ones-MFMA -> every lane holds l[m].
// V streamed from L2 (per-XCD V = 2 MB, L2-resident), single-buffered
// with ~200cy compute gap; K double-buffered one chunk ahead.
// ---------------------------------------------------------------------------
__global__ __launch_bounds__(256, 2) void attn_kernel(
    const u16* __restrict__ qt, const u16* __restrict__ kt,
    const u16* __restrict__ vv, const float* __restrict__ x,
    const float* __restrict__ gamma_p, float* __restrict__ out)
{
    // XCD-aware decode: wg->XCD is round-robin on linear id (id%8).
    const int bid  = blockIdx.x;
    const int xcd  = bid & 7;
    const int slot = bid >> 3;                 // 0..63 within XCD
    const int b    = (xcd << 2) | (slot >> 4); // 4 batches per XCD
    const int m0b  = (slot & 15) * 64;

    const int t = threadIdx.x, lane = t & 63, w = t >> 6;  // w 0..3
    const int quad = lane >> 4, c16 = lane & 15;
    const int m0 = m0b + (w & 1) * 32;        // wave's 32-row m base
    const int c0 = (w >> 1) * 128;            // wave's 128-channel base

    // Q B-frags (B[k=d][col=m]): lane holds Q[m0+mt*16+c16][d=quad*8+j]
    bf16x8 qa[2];
#pragma unroll
    for (int mt = 0; mt < 2; ++mt)
        qa[mt] = *(const bf16x8*)&qt[((size_t)b * NN + m0 + mt * 16 + c16) * CQ + quad * 8];

    bf16x8 ones;
#pragma unroll
    for (int j = 0; j < 8; ++j) ones[j] = (short)0x3F80;   // bf16 1.0

    f32x4 accO[8][2];                // [cs][mt] of O^T: row=c, col=m
    f32x4 lsum[2];                   // rows identical -> l[m=c16] everywhere
#pragma unroll
    for (int mt = 0; mt < 2; ++mt) {
        lsum[mt] = (f32x4){0.f, 0.f, 0.f, 0.f};
#pragma unroll
        for (int cs = 0; cs < 8; ++cs) accO[cs][mt] = (f32x4){0.f, 0.f, 0.f, 0.f};
    }

    const u16* vb = vv + (size_t)b * CC * NN;   // V[c][n]
    const u16* kp = kt + (size_t)b * NN * CQ;   // K-perm[n'][d]

    // pre-issue K A-frags for chunk 0 (A[row][k=d]; rows are permuted K rows:
    // row c16 of tile tt holds K row (c16>>2)*8 + tt*4 + (c16&3))
    bf16x8 kbA[2], kbB[2];
#pragma unroll
    for (int tt = 0; tt < 2; ++tt)
        kbA[tt] = *(const bf16x8*)&kp[(size_t)(tt * 16 + c16) * CQ + quad * 8];

    auto CHUNK = [&](int cb, bf16x8 (&kbC)[2], bf16x8 (&kbN)[2]) {
        const int nb = cb * 32;
        // V A-frags for this chunk (8 x b128; consumed after S'+exp,
        // ~200cy gap covers L2 latency)
        bf16x8 va[8];
#pragma unroll
        for (int cs = 0; cs < 8; ++cs)
            va[cs] = *(const bf16x8*)&vb[(size_t)(c0 + cs * 16 + c16) * NN + nb + quad * 8];
        // prefetch K frags for next chunk (full-chunk latency cover)
        if (cb + 1 < 32) {
#pragma unroll
            for (int tt = 0; tt < 2; ++tt)
                kbN[tt] = *(const bf16x8*)&kp[(size_t)(nb + 32 + tt * 16 + c16) * CQ + quad * 8];
        }
#pragma unroll
        for (int mt = 0; mt < 2; ++mt) {
            // S'^T = mfma(K_perm, Q): lane(quad,c16) reg r holds
            // S[m=c16][n = nb + quad*8 + tt*4 + r]  (per kt permutation)
            f32x4 s0 = __builtin_amdgcn_mfma_f32_16x16x32_bf16(
                kbC[0], qa[mt], (f32x4){0.f, 0.f, 0.f, 0.f}, 0, 0, 0);
            f32x4 s1 = __builtin_amdgcn_mfma_f32_16x16x32_bf16(
                kbC[1], qa[mt], (f32x4){0.f, 0.f, 0.f, 0.f}, 0, 0, 0);
            // P = exp(S) -> bf16, packed DIRECTLY into PV B-frag order
            // (k = quad*8 + j, j = tt*4 + r): no cross-lane, no LDS.
            union { unsigned u[4]; bf16x8 v; } pu;
            pu.u[0] = cvt_pk_bf16(__expf(s0[0]), __expf(s0[1]));
            pu.u[1] = cvt_pk_bf16(__expf(s0[2]), __expf(s0[3]));
            pu.u[2] = cvt_pk_bf16(__expf(s1[0]), __expf(s1[1]));
            pu.u[3] = cvt_pk_bf16(__expf(s1[2]), __expf(s1[3]));
            const bf16x8 pb = pu.v;
            lsum[mt] = __builtin_amdgcn_mfma_f32_16x16x32_bf16(ones, pb, lsum[mt], 0, 0, 0);
#pragma unroll
            for (int cs = 0; cs < 8; ++cs)
                accO[cs][mt] = __builtin_amdgcn_mfma_f32_16x16x32_bf16(
                    va[cs], pb, accO[cs][mt], 0, 0, 0);
        }
    };

#pragma unroll 1
    for (int cb = 0; cb < 32; cb += 2) {      // 2-chunk unroll: kbA/kbB swap
        CHUNK(cb,     kbA, kbB);
        CHUNK(cb + 1, kbB, kbA);
    }

    // ---- epilogue: out = gamma * O / l + x ----
    const float gamma = gamma_p[0];
#pragma unroll
    for (int mt = 0; mt < 2; ++mt) {
        const float inv = gamma / lsum[mt][0];   // all rows identical
        const int m = m0 + mt * 16 + c16;
#pragma unroll
        for (int cs = 0; cs < 8; ++cs) {
            const int cb2 = c0 + cs * 16 + quad * 4;
#pragma unroll
            for (int r = 0; r < 4; ++r) {
                const size_t idx = ((size_t)b * CC + cb2 + r) * NN + m;
                out[idx] = accO[cs][mt][r] * inv + x[idx];
            }
        }
    }
}

// ---------------------------------------------------------------------------
extern "C" void kernel_launch(void* const* d_in, const int* in_sizes, int n_in,
                              void* d_out, int out_size, void* d_ws, size_t ws_size,
                              hipStream_t stream)
{
    const float* x  = (const float*)d_in[0];
    const float* Wq = (const float*)d_in[1];
    const float* bq = (const float*)d_in[2];
    const float* Wk = (const float*)d_in[3];
    const float* bk = (const float*)d_in[4];
    const float* Wv = (const float*)d_in[5];
    const float* bv = (const float*)d_in[6];
    const float* gm = (const float*)d_in[7];
    float* out = (float*)d_out;

    // workspace (bf16): qt 2MB | kt 2MB | vv 16MB | wfrag 160KB
    u16* qt    = (u16*)d_ws;
    u16* kt    = qt + (size_t)BB * NN * CQ;
    u16* vv    = kt + (size_t)BB * NN * CQ;
    u16* wfrag = vv + (size_t)BB * CC * NN;

    wpack_kernel<<<320, 256, 0, stream>>>(Wq, Wk, Wv, wfrag);
    dim3 grid(32, BB);
    qkv_kernel<<<grid, 256, 0, stream>>>(x, wfrag, bq, bk, bv, qt, kt, vv);
    attn_kernel<<<512, 256, 0, stream>>>(qt, kt, vv, x, gm, out);
}